// Round 1
// baseline (3859.806 us; speedup 1.0000x reference)
//
// Round 1: Seq2Seq LSTM (beam search collapses to plain teacher-forced decode).
// Design: batch-parallel persistent-per-WG kernel, 32 WGs x 512 thr, bf16 MFMA,
// weights packed bf16 (gate-interleaved) by prep kernel, h/x in LDS, c in regs.
#include <hip/hip_runtime.h>

typedef unsigned short u16;
typedef unsigned int   u32;
typedef __attribute__((ext_vector_type(8))) short bf16x8;  // 8 bf16 (4 VGPRs)
typedef __attribute__((ext_vector_type(4))) float f32x4;   // MFMA C/D frag

#define DEVINL static __device__ __forceinline__

DEVINL u16 f2bf(float f){ u32 x = __float_as_uint(f); return (u16)((x + 0x7fffu + ((x>>16)&1u)) >> 16); }
DEVINL float bf2f(u16 u){ return __uint_as_float(((u32)u) << 16); }
DEVINL u32 pack2(float a, float b){ return (u32)f2bf(a) | ((u32)f2bf(b) << 16); }
DEVINL float sigm(float x){ return 1.f/(1.f + __expf(-x)); }
DEVINL float tanhs(float x){ float xc = fminf(fmaxf(x,-15.f),15.f); float e = __expf(2.f*xc); return (e-1.f)/(e+1.f); }

// ---------------- prep: pack weights to bf16 with row permutation j' = u*4+gate
// matrix order m: 0 eIH_l0, 1 eHH_l0, 2 eIH_l1, 3 eHH_l1, 4 dIH_l0, 5 dHH_l0, 6 dIH_l1, 7 dHH_l1
__global__ void pack_all(const float* __restrict__ eih, const float* __restrict__ ehh,
                         const float* __restrict__ dih, const float* __restrict__ dhh,
                         const float* __restrict__ ebi, const float* __restrict__ ebh,
                         const float* __restrict__ dbi, const float* __restrict__ dbh,
                         u16* __restrict__ wout, float* __restrict__ bout){
  int blk = blockIdx.x, t = threadIdx.x;
  if (blk < 8192){
    int m = blk >> 10, j2 = blk & 1023;
    const float* base = (m < 4) ? ((m & 1) ? ehh : eih) : ((m & 1) ? dhh : dih);
    const float* S = base + (size_t)((m >> 1) & 1) * 262144;  // layer select
    int u = j2 >> 2, g = j2 & 3, j = g*256 + u;
    wout[(size_t)blk*256 + t] = f2bf(S[(size_t)j*256 + t]);
  } else {
    int idx = (blk - 8192)*256 + t;             // 0..4095 : [phase][layer][j']
    int phase = idx >> 11, l = (idx >> 10) & 1, j2 = idx & 1023;
    int u = j2 >> 2, g = j2 & 3, j = g*256 + u;
    const float* bi = phase ? dbi : ebi;
    const float* bh = phase ? dbh : ebh;
    bout[idx] = bi[l*1024 + j] + bh[l*1024 + j];
  }
}

// ---------------- main recurrent kernel: 32 WGs, each owns 16 batch rows, loops 63 steps
#define SMEM_BYTES 124368

__global__ void __launch_bounds__(512, 2)
lstm_main(const int* __restrict__ src, const float* __restrict__ enc_emb,
          const float* __restrict__ dec_emb, const u16* __restrict__ wpack,
          const float* __restrict__ bpack, const float* __restrict__ fcW,
          const float* __restrict__ fcb, float* __restrict__ out){
  extern __shared__ char smem[];
  u16*   h_sh    = (u16*)(smem);             // [2 layers][16][264] bf16 (pad 264 -> 2-way banks)
  u16*   x_sh    = (u16*)(smem + 16896);     // [2 parity][16][264] bf16
  float* G_sh    = (float*)(smem + 33792);   // [16][1032] f32 gate pre-activations
  float* bias_sh = (float*)(smem + 99840);   // [4][1024]  (bih+bhh, permuted)
  float* fcw_sh  = (float*)(smem + 116224);  // [4][256]
  float* fcb_sh  = (float*)(smem + 120320);  // [4]
  int*   tok_sh  = (int*)(smem + 120336);    // [63][16]

  const int tid  = threadIdx.x;
  const int w    = tid >> 6;          // wave 0..7, owns 128 gate-cols
  const int lane = tid & 63;
  const int arow = lane & 15;         // MFMA A row / D col
  const int agrp = lane >> 4;         // MFMA k-group
  const int gb   = tid >> 5;          // gate phase: batch row 0..15
  const int gu   = tid & 31;          // gate phase: base hidden unit
  const int wgb0 = blockIdx.x << 4;

  // ---- prologue staging
  for (int idx = tid; idx < 63*16; idx += 512){
    int s = idx >> 4, i = idx & 15;
    int t = (s < 31) ? (31 - s) : (s - 31);   // enc reversed, then dec forward
    tok_sh[idx] = src[t*512 + wgb0 + i];
  }
  for (int idx = tid; idx < 4096; idx += 512) bias_sh[idx] = bpack[idx];
  for (int idx = tid; idx < 1024; idx += 512) fcw_sh[idx] = fcW[idx];
  if (tid < 4) fcb_sh[tid] = fcb[tid];
  for (int idx = tid; idx < 4224; idx += 512) ((u32*)h_sh)[idx] = 0u;  // h1=h2=0
  __syncthreads();
  {     // x for step 0
    int tok = tok_sh[gb];
    const float* erow = enc_emb + (size_t)tok*256 + gu*8;
    float4 a = *(const float4*)erow;
    float4 b = *(const float4*)(erow + 4);
    u32* dst = (u32*)(x_sh + gb*264 + gu*8);
    dst[0]=pack2(a.x,a.y); dst[1]=pack2(a.z,a.w); dst[2]=pack2(b.x,b.y); dst[3]=pack2(b.z,b.w);
  }
  float c1[8], c2[8];
  #pragma unroll
  for (int i=0;i<8;i++){ c1[i]=0.f; c2[i]=0.f; }
  __syncthreads();

  for (int step = 0; step < 63; ++step){
    const int phase = (step < 31) ? 0 : 1;    // enc / dec
    const int par   = step & 1;
    const u16* Wb   = wpack + (size_t)phase * 4 * 262144;

    // prefetch next step's embedding row into regs (hidden under matmul)
    float4 xp0, xp1; const bool has = (step+1) < 63;
    if (has){
      int tok = tok_sh[(step+1)*16 + gb];
      const float* erow = (((step+1) < 31) ? enc_emb : dec_emb) + (size_t)tok*256 + gu*8;
      xp0 = *(const float4*)erow; xp1 = *(const float4*)(erow + 4);
    }

    // ---------- layer 1 matmul: G = [x ; h1] @ [Wih1 ; Whh1]^T
    {
      bf16x8 Ax[8], Ah[8];
      const u16* xb = x_sh + par*4224 + arow*264 + agrp*8;
      const u16* hb = h_sh +            arow*264 + agrp*8;
      #pragma unroll
      for (int kk=0;kk<8;kk++){ Ax[kk] = *(const bf16x8*)(xb + kk*32); Ah[kk] = *(const bf16x8*)(hb + kk*32); }
      const u16* Bih = Wb;
      const u16* Bhh = Wb + 262144;
      #pragma unroll
      for (int ct=0; ct<8; ++ct){
        const int col = (w<<7) + (ct<<4) + arow;
        const u16* p0 = Bih + col*256 + agrp*8;
        const u16* p1 = Bhh + col*256 + agrp*8;
        f32x4 acc = {0.f,0.f,0.f,0.f};
        #pragma unroll
        for (int kk=0;kk<8;kk++) acc = __builtin_amdgcn_mfma_f32_16x16x32_bf16(Ax[kk], *(const bf16x8*)(p0 + kk*32), acc, 0,0,0);
        #pragma unroll
        for (int kk=0;kk<8;kk++) acc = __builtin_amdgcn_mfma_f32_16x16x32_bf16(Ah[kk], *(const bf16x8*)(p1 + kk*32), acc, 0,0,0);
        #pragma unroll
        for (int r=0;r<4;r++) G_sh[(agrp*4+r)*1032 + col] = acc[r];
      }
    }
    __syncthreads();
    // ---------- gate 1 (+ write prefetched x)
    {
      const float* brow = bias_sh + (phase*2+0)*1024;
      #pragma unroll
      for (int i=0;i<8;++i){
        int u = gu + (i<<5);
        float4 g4 = *(const float4*)(G_sh + gb*1032 + (u<<2));
        float4 b4 = *(const float4*)(brow + (u<<2));
        float I = sigm(g4.x + b4.x), F = sigm(g4.y + b4.y);
        float Gg = tanhs(g4.z + b4.z), O = sigm(g4.w + b4.w);
        float cn = F*c1[i] + I*Gg;
        c1[i] = cn;
        h_sh[gb*264 + u] = f2bf(O * tanhs(cn));
      }
      if (has){
        u32* dst = (u32*)(x_sh + ((step+1)&1)*4224 + gb*264 + gu*8);
        dst[0]=pack2(xp0.x,xp0.y); dst[1]=pack2(xp0.z,xp0.w); dst[2]=pack2(xp1.x,xp1.y); dst[3]=pack2(xp1.z,xp1.w);
      }
    }
    __syncthreads();
    // ---------- layer 2 matmul: G = [h1_new ; h2_old] @ [Wih2 ; Whh2]^T
    {
      bf16x8 A1[8], A2[8];
      const u16* h1b = h_sh +        arow*264 + agrp*8;
      const u16* h2b = h_sh + 4224 + arow*264 + agrp*8;
      #pragma unroll
      for (int kk=0;kk<8;kk++){ A1[kk] = *(const bf16x8*)(h1b + kk*32); A2[kk] = *(const bf16x8*)(h2b + kk*32); }
      const u16* Bih = Wb + 2*262144;
      const u16* Bhh = Wb + 3*262144;
      #pragma unroll
      for (int ct=0; ct<8; ++ct){
        const int col = (w<<7) + (ct<<4) + arow;
        const u16* p0 = Bih + col*256 + agrp*8;
        const u16* p1 = Bhh + col*256 + agrp*8;
        f32x4 acc = {0.f,0.f,0.f,0.f};
        #pragma unroll
        for (int kk=0;kk<8;kk++) acc = __builtin_amdgcn_mfma_f32_16x16x32_bf16(A1[kk], *(const bf16x8*)(p0 + kk*32), acc, 0,0,0);
        #pragma unroll
        for (int kk=0;kk<8;kk++) acc = __builtin_amdgcn_mfma_f32_16x16x32_bf16(A2[kk], *(const bf16x8*)(p1 + kk*32), acc, 0,0,0);
        #pragma unroll
        for (int r=0;r<4;r++) G_sh[(agrp*4+r)*1032 + col] = acc[r];
      }
    }
    __syncthreads();
    // ---------- gate 2
    {
      const float* brow = bias_sh + (phase*2+1)*1024;
      #pragma unroll
      for (int i=0;i<8;++i){
        int u = gu + (i<<5);
        float4 g4 = *(const float4*)(G_sh + gb*1032 + (u<<2));
        float4 b4 = *(const float4*)(brow + (u<<2));
        float I = sigm(g4.x + b4.x), F = sigm(g4.y + b4.y);
        float Gg = tanhs(g4.z + b4.z), O = sigm(g4.w + b4.w);
        float cn = F*c2[i] + I*Gg;
        c2[i] = cn;
        h_sh[4224 + gb*264 + u] = f2bf(O * tanhs(cn));
      }
    }
    __syncthreads();
    // ---------- fc + log_softmax over 4 classes (decoder steps), wave 0 only
    if (phase && tid < 64){
      int b = tid >> 2, v = tid & 3;
      const u16* hrow = h_sh + 4224 + b*264;
      const float* wrow = fcw_sh + (v<<8);
      float s = 0.f;
      #pragma unroll
      for (int u8=0; u8<32; ++u8){
        bf16x8 hv = *(const bf16x8*)(hrow + u8*8);
        const float4 wa = *(const float4*)(wrow + u8*8);
        const float4 wb = *(const float4*)(wrow + u8*8 + 4);
        s += bf2f((u16)hv[0])*wa.x + bf2f((u16)hv[1])*wa.y + bf2f((u16)hv[2])*wa.z + bf2f((u16)hv[3])*wa.w
           + bf2f((u16)hv[4])*wb.x + bf2f((u16)hv[5])*wb.y + bf2f((u16)hv[6])*wb.z + bf2f((u16)hv[7])*wb.w;
      }
      s += fcb_sh[v];
      float m = fmaxf(s, __shfl_xor(s,1)); m = fmaxf(m, __shfl_xor(m,2));
      float e = __expf(s - m);
      float es = e + __shfl_xor(e,1); es += __shfl_xor(es,2);
      out[((size_t)(step-31)*512 + wgb0 + b)*4 + v] = s - m - __logf(es);
    }
  }
}

extern "C" void kernel_launch(void* const* d_in, const int* in_sizes, int n_in,
                              void* d_out, int out_size, void* d_ws, size_t ws_size,
                              hipStream_t stream){
  const int*   src     = (const int*)  d_in[0];
  const float* enc_emb = (const float*)d_in[2];
  const float* enc_Wih = (const float*)d_in[3];
  const float* enc_Whh = (const float*)d_in[4];
  const float* enc_bih = (const float*)d_in[5];
  const float* enc_bhh = (const float*)d_in[6];
  const float* dec_emb = (const float*)d_in[7];
  const float* dec_Wih = (const float*)d_in[8];
  const float* dec_Whh = (const float*)d_in[9];
  const float* dec_bih = (const float*)d_in[10];
  const float* dec_bhh = (const float*)d_in[11];
  const float* fcW     = (const float*)d_in[12];
  const float* fcb     = (const float*)d_in[13];
  float* out = (float*)d_out;
  u16*   wpack = (u16*)d_ws;                               // 4 MB packed bf16 weights
  float* bpack = (float*)((char*)d_ws + (size_t)8*262144*2); // 16 KB combined biases
  (void)in_sizes; (void)n_in; (void)out_size; (void)ws_size;

  hipFuncSetAttribute((const void*)lstm_main, hipFuncAttributeMaxDynamicSharedMemorySize, SMEM_BYTES);
  pack_all<<<8208, 256, 0, stream>>>(enc_Wih, enc_Whh, dec_Wih, dec_Whh,
                                     enc_bih, enc_bhh, dec_bih, dec_bhh, wpack, bpack);
  lstm_main<<<32, 512, SMEM_BYTES, stream>>>(src, enc_emb, dec_emb, wpack, bpack, fcW, fcb, out);
}

// Round 2
// 2391.866 us; speedup vs baseline: 1.6137x; 1.6137x over previous
//
// Round 2: weight-stationary registers + 2-way gate-column split across WG pairs.
// 64 WGs x 1024 thr. Weights live in VGPRs (256/wave, reloaded at enc->dec switch).
// Swapped MFMA operands (D = W * act): lane owns all 4 gates of one (unit,row).
// Pair h-exchange via agent-scope relaxed atomics (IC-coherent) + monotonic flags.
#include <hip/hip_runtime.h>

typedef unsigned short u16;
typedef unsigned int   u32;
typedef __attribute__((ext_vector_type(8))) short bf16x8;  // 8 bf16 (4 VGPRs)
typedef __attribute__((ext_vector_type(4))) float f32x4;   // MFMA C/D frag

#define DEVINL static __device__ __forceinline__
#define MFMA __builtin_amdgcn_mfma_f32_16x16x32_bf16

DEVINL u16 f2bf(float f){ u32 x = __float_as_uint(f); return (u16)((x + 0x7fffu + ((x>>16)&1u)) >> 16); }
DEVINL float bf2f(u16 u){ return __uint_as_float(((u32)u) << 16); }
DEVINL u32 pack2(float a, float b){ return (u32)f2bf(a) | ((u32)f2bf(b) << 16); }
DEVINL float sigm(float x){ return 1.f/(1.f + __expf(-x)); }
DEVINL float tanhs(float x){ float xc = fminf(fmaxf(x,-15.f),15.f); float e = __expf(2.f*xc); return (e-1.f)/(e+1.f); }

// ---------------- prep: pack weights to bf16 with row permutation j' = u*4+gate
// matrix order m: 0 eIH_l0, 1 eHH_l0, 2 eIH_l1, 3 eHH_l1, 4 dIH_l0, 5 dHH_l0, 6 dIH_l1, 7 dHH_l1
__global__ void pack_all(const float* __restrict__ eih, const float* __restrict__ ehh,
                         const float* __restrict__ dih, const float* __restrict__ dhh,
                         const float* __restrict__ ebi, const float* __restrict__ ebh,
                         const float* __restrict__ dbi, const float* __restrict__ dbh,
                         u16* __restrict__ wout, float* __restrict__ bout,
                         u32* __restrict__ flags){
  int blk = blockIdx.x, t = threadIdx.x;
  if (blk < 8192){
    int m = blk >> 10, j2 = blk & 1023;
    const float* base = (m < 4) ? ((m & 1) ? ehh : eih) : ((m & 1) ? dhh : dih);
    const float* S = base + (size_t)((m >> 1) & 1) * 262144;  // layer select
    int u = j2 >> 2, g = j2 & 3, j = g*256 + u;
    wout[(size_t)blk*256 + t] = f2bf(S[(size_t)j*256 + t]);
  } else if (blk < 8208){
    int idx = (blk - 8192)*256 + t;             // 0..4095 : [phase][layer][j']
    int phase = idx >> 11, l = (idx >> 10) & 1, j2 = idx & 1023;
    int u = j2 >> 2, g = j2 & 3, j = g*256 + u;
    const float* bi = phase ? dbi : ebi;
    const float* bh = phase ? dbh : ebh;
    bout[idx] = bi[l*1024 + j] + bh[l*1024 + j];
  } else {
    for (int i = t; i < 2048; i += 256) flags[i] = 0u;   // flag reset EVERY call
  }
}

struct SM {
  u16   A1[16][520];      // [x(t) 0..255 | h1(t-1) 256..511] bf16, pad stride 520
  u16   A2[16][520];      // [h1(t) 0..255 | h2(t-1)/h2(t) 256..511]
  float bias[2][2][512];  // [phase][layer][local j' 0..511] (bih+bhh)
  float fcw[4][256];
  float fcb[4];
  int   tok[63][16];
};

__global__ void __launch_bounds__(1024, 4)
lstm_main(const int* __restrict__ src, const float* __restrict__ enc_emb,
          const float* __restrict__ dec_emb, const u16* __restrict__ wpack,
          const float* __restrict__ bpack, const float* __restrict__ fcW,
          const float* __restrict__ fcb, float* __restrict__ out,
          u32* __restrict__ H1w, u32* __restrict__ H2w, u32* __restrict__ flags)
{
  __shared__ SM sm;
  const int tid  = threadIdx.x;
  const int wv   = tid >> 6;         // wave 0..15
  const int lane = tid & 63;
  const int agrp = lane >> 4;        // MFMA k-group / unit-in-tile
  const int n    = lane & 15;        // MFMA N col = batch row
  const int wg   = blockIdx.x, bg = wg >> 1, g = wg & 1, pg = g ^ 1, pwg = wg ^ 1;
  const int wgb0 = bg << 4;
  const int xr   = tid >> 6, xc = (tid & 63) << 2;   // x-gather: row, col4

  // ---- prologue staging
  for (int i = tid; i < 1008; i += 1024){
    int s = i >> 4, b = i & 15;
    int t = (s < 31) ? (31 - s) : (s - 31);          // enc reversed, dec forward
    sm.tok[s][b] = src[t*512 + wgb0 + b];
  }
  for (int i = tid; i < 2048; i += 1024){
    int ph = i >> 10, l = (i >> 9) & 1, j = i & 511;
    sm.bias[ph][l][j] = bpack[(ph*2 + l)*1024 + g*512 + j];
  }
  ((float*)sm.fcw)[tid] = fcW[tid];
  if (tid < 4) sm.fcb[tid] = fcb[tid];
  for (int i = tid; i < 2048; i += 1024){            // h1(-1)=h2(-1)=0
    int r = i >> 7, cc = (i & 127) << 1;
    *(u32*)&sm.A1[r][256 + cc] = 0u;
    *(u32*)&sm.A2[r][256 + cc] = 0u;
  }
  __syncthreads();
  { // x(0)
    int tk = sm.tok[0][xr];
    float4 v = *(const float4*)(enc_emb + (size_t)tk*256 + xc);
    u32* d = (u32*)&sm.A1[xr][xc];
    d[0] = pack2(v.x, v.y); d[1] = pack2(v.z, v.w);
  }

  // ---- weight-stationary register state
  bf16x8 W[2][2][16];        // [layer][ct][kk]  (256 VGPRs)
  float4 br[2][2];           // bias per (layer, ct) for this lane's unit
  float  cst[2][2] = {{0.f,0.f},{0.f,0.f}};

  auto LOADW = [&](int ph){
    const u16* base = wpack + (size_t)ph * 1048576;
    #pragma unroll
    for (int l = 0; l < 2; l++){
      #pragma unroll
      for (int c = 0; c < 2; c++){
        const int jrow = (g << 9) + ((wv*2 + c) << 4) + n;   // W row (gate-col j')
        #pragma unroll
        for (int kk = 0; kk < 16; kk++){
          const u16* mp = base + (size_t)((l << 1) + (kk >> 3))*262144
                        + (size_t)jrow*256 + ((kk & 7) << 5) + (agrp << 3);
          W[l][c][kk] = *(const bf16x8*)mp;
        }
        const int ul = (wv << 3) + (c << 2) + agrp;
        br[l][c] = *(const float4*)&sm.bias[ph][l][ul << 2];
      }
    }
  };
  LOADW(0);
  __syncthreads();

  for (int t = 0; t < 63; ++t){
    if (t == 31) LOADW(1);                     // enc -> dec phase switch
    // ---- layer-1 act frags from A1 = [x(t) | h1(t-1)]
    bf16x8 act[16];
    #pragma unroll
    for (int kk = 0; kk < 16; kk++)
      act[kk] = *(const bf16x8*)&sm.A1[n][(kk << 5) + (agrp << 3)];
    // prefetch x(t+1)
    u32 xp0 = 0, xp1 = 0;
    if (t + 1 < 63){
      int tk = sm.tok[t+1][xr];
      const float* e = ((t+1 < 31) ? enc_emb : dec_emb) + (size_t)tk*256 + xc;
      float4 v = *(const float4*)e;
      xp0 = pack2(v.x, v.y); xp1 = pack2(v.z, v.w);
    }
    // ---- l1 MFMA: D = W * act  (lane: unit=tile*4+agrp, col n = batch row)
    f32x4 a0 = {0.f,0.f,0.f,0.f}, a1 = {0.f,0.f,0.f,0.f};
    #pragma unroll
    for (int kk = 0; kk < 16; kk++){
      a0 = MFMA(W[0][0][kk], act[kk], a0, 0, 0, 0);
      a1 = MFMA(W[0][1][kk], act[kk], a1, 0, 0, 0);
    }
    __syncthreads();                                           // S1
    // ---- gate1: lane owns (unit ul, row n), 4 gates in acc regs
    #pragma unroll
    for (int c = 0; c < 2; c++){
      f32x4 a = c ? a1 : a0;
      float4 b = br[0][c];
      float I = sigm(a[0] + b.x), F = sigm(a[1] + b.y);
      float G = tanhs(a[2] + b.z), O = sigm(a[3] + b.w);
      float cn = F*cst[0][c] + I*G;
      cst[0][c] = cn;
      u16 hb = f2bf(O * tanhs(cn));
      const int ul = (wv << 3) + (c << 2) + agrp;
      sm.A1[n][256 + (g << 7) + ul] = hb;                      // for l1(t+1)
      sm.A2[n][(g << 7) + ul] = hb;                            // for l2(t)
      u32 other = (u32)__shfl_xor((int)(u32)hb, 16);
      if ((agrp & 1) == 0){
        u32 hv = (u32)hb | (other << 16);
        __hip_atomic_store(&H1w[(size_t)(wgb0 + n)*128 + (g << 6) + (ul >> 1)],
                           hv, __ATOMIC_RELAXED, __HIP_MEMORY_SCOPE_AGENT);
      }
    }
    if (t + 1 < 63){                                           // x(t+1) -> A1
      u32* d = (u32*)&sm.A1[xr][xc];
      d[0] = xp0; d[1] = xp1;
    }
    __syncthreads();                                           // S2 (stores drained)
    if (tid == 0){
      __hip_atomic_store(&flags[wg*32], (u32)(t+1), __ATOMIC_RELAXED, __HIP_MEMORY_SCOPE_AGENT);
      asm volatile("" ::: "memory");
      while (__hip_atomic_load(&flags[pwg*32], __ATOMIC_RELAXED, __HIP_MEMORY_SCOPE_AGENT) < (u32)(t+1))
        __builtin_amdgcn_s_sleep(2);
    }
    __syncthreads();                                           // S3
    { // fill partner h1(t) -> A2 (l2 now) and A1 (l1 next step)
      int r = tid >> 6, wd = tid & 63;
      u32 v = __hip_atomic_load(&H1w[(size_t)(wgb0 + r)*128 + (pg << 6) + wd],
                                __ATOMIC_RELAXED, __HIP_MEMORY_SCOPE_AGENT);
      int pu = (pg << 7) + (wd << 1);
      *(u32*)&sm.A2[r][pu] = v;
      *(u32*)&sm.A1[r][256 + pu] = v;
    }
    __syncthreads();                                           // S4
    // ---- layer-2 act frags from A2 = [h1(t) | h2(t-1)]
    #pragma unroll
    for (int kk = 0; kk < 16; kk++)
      act[kk] = *(const bf16x8*)&sm.A2[n][(kk << 5) + (agrp << 3)];
    f32x4 b0 = {0.f,0.f,0.f,0.f}, b1 = {0.f,0.f,0.f,0.f};
    #pragma unroll
    for (int kk = 0; kk < 16; kk++){
      b0 = MFMA(W[1][0][kk], act[kk], b0, 0, 0, 0);
      b1 = MFMA(W[1][1][kk], act[kk], b1, 0, 0, 0);
    }
    __syncthreads();                                           // S5
    // ---- gate2
    #pragma unroll
    for (int c = 0; c < 2; c++){
      f32x4 a = c ? b1 : b0;
      float4 b = br[1][c];
      float I = sigm(a[0] + b.x), F = sigm(a[1] + b.y);
      float G = tanhs(a[2] + b.z), O = sigm(a[3] + b.w);
      float cn = F*cst[1][c] + I*G;
      cst[1][c] = cn;
      u16 hb = f2bf(O * tanhs(cn));
      const int ul = (wv << 3) + (c << 2) + agrp;
      sm.A2[n][256 + (g << 7) + ul] = hb;                      // h2(t) for l2(t+1)+fc
      u32 other = (u32)__shfl_xor((int)(u32)hb, 16);
      if ((agrp & 1) == 0){
        u32 hv = (u32)hb | (other << 16);
        __hip_atomic_store(&H2w[(size_t)(wgb0 + n)*128 + (g << 6) + (ul >> 1)],
                           hv, __ATOMIC_RELAXED, __HIP_MEMORY_SCOPE_AGENT);
      }
    }
    __syncthreads();                                           // S6
    if (tid == 0){
      __hip_atomic_store(&flags[wg*32 + 16], (u32)(t+1), __ATOMIC_RELAXED, __HIP_MEMORY_SCOPE_AGENT);
      asm volatile("" ::: "memory");
      while (__hip_atomic_load(&flags[pwg*32 + 16], __ATOMIC_RELAXED, __HIP_MEMORY_SCOPE_AGENT) < (u32)(t+1))
        __builtin_amdgcn_s_sleep(2);
    }
    __syncthreads();                                           // S7
    { // fill partner h2(t) -> A2
      int r = tid >> 6, wd = tid & 63;
      u32 v = __hip_atomic_load(&H2w[(size_t)(wgb0 + r)*128 + (pg << 6) + wd],
                                __ATOMIC_RELAXED, __HIP_MEMORY_SCOPE_AGENT);
      *(u32*)&sm.A2[r][256 + (pg << 7) + (wd << 1)] = v;
    }
    __syncthreads();                                           // S8
    // ---- fc + log_softmax (decoder): wave0, 32 lanes; g=0 rows 0-7, g=1 rows 8-15
    if (t >= 31 && tid < 32){
      const int v = tid & 3, bl = (g << 3) + (tid >> 2);
      float s = sm.fcb[v];
      #pragma unroll
      for (int q = 0; q < 32; q++){
        bf16x8 hv = *(const bf16x8*)&sm.A2[bl][256 + (q << 3)];
        const float* wr = &sm.fcw[v][q << 3];
        s += bf2f((u16)hv[0])*wr[0] + bf2f((u16)hv[1])*wr[1]
           + bf2f((u16)hv[2])*wr[2] + bf2f((u16)hv[3])*wr[3]
           + bf2f((u16)hv[4])*wr[4] + bf2f((u16)hv[5])*wr[5]
           + bf2f((u16)hv[6])*wr[6] + bf2f((u16)hv[7])*wr[7];
      }
      float m = fmaxf(s, __shfl_xor(s, 1)); m = fmaxf(m, __shfl_xor(m, 2));
      float e = __expf(s - m);
      float es = e + __shfl_xor(e, 1); es += __shfl_xor(es, 2);
      out[((size_t)(t - 31)*512 + wgb0 + bl)*4 + v] = s - m - __logf(es);
    }
  }
}

extern "C" void kernel_launch(void* const* d_in, const int* in_sizes, int n_in,
                              void* d_out, int out_size, void* d_ws, size_t ws_size,
                              hipStream_t stream){
  const int*   src     = (const int*)  d_in[0];
  const float* enc_emb = (const float*)d_in[2];
  const float* enc_Wih = (const float*)d_in[3];
  const float* enc_Whh = (const float*)d_in[4];
  const float* enc_bih = (const float*)d_in[5];
  const float* enc_bhh = (const float*)d_in[6];
  const float* dec_emb = (const float*)d_in[7];
  const float* dec_Wih = (const float*)d_in[8];
  const float* dec_Whh = (const float*)d_in[9];
  const float* dec_bih = (const float*)d_in[10];
  const float* dec_bhh = (const float*)d_in[11];
  const float* fcW     = (const float*)d_in[12];
  const float* fcb     = (const float*)d_in[13];
  float* out = (float*)d_out;
  (void)in_sizes; (void)n_in; (void)out_size; (void)ws_size;

  // ws layout: wpack 4MB | bpack 16KB | H1w 256KB | H2w 256KB | flags 8KB  (~4.5MB)
  u16*   wpack = (u16*)d_ws;
  float* bpack = (float*)((char*)d_ws + 4194304);
  u32*   H1w   = (u32*)((char*)d_ws + 4194304 + 16384);
  u32*   H2w   = (u32*)((char*)d_ws + 4194304 + 16384 + 262144);
  u32*   flags = (u32*)((char*)d_ws + 4194304 + 16384 + 524288);

  pack_all<<<8209, 256, 0, stream>>>(enc_Wih, enc_Whh, dec_Wih, dec_Whh,
                                     enc_bih, enc_bhh, dec_bih, dec_bhh,
                                     wpack, bpack, flags);
  lstm_main<<<64, 1024, 0, stream>>>(src, enc_emb, dec_emb, wpack, bpack,
                                     fcW, fcb, out, H1w, H2w, flags);
}

// Round 3
// 607.172 us; speedup vs baseline: 6.3570x; 3.9394x over previous
//
// Round 3: true weight-stationary. 256 WGs x 512 thr (1/CU, 8 waves @ <=256 VGPR).
// Group = 8 WGs / 16 batch rows; wave holds W[2][16] = 128 VGPR (both layers, 16 gate-cols).
// Per-step h1/h2 allgather via relaxed agent atomics + monotonic flags, parity-dbuf'd H.
// Group members share blockIdx%8 -> same XCD (perf heuristic only; protocol is chip-coherent).
#include <hip/hip_runtime.h>

typedef unsigned short u16;
typedef unsigned int   u32;
typedef __attribute__((ext_vector_type(8))) short bf16x8;  // 8 bf16 (4 VGPRs)
typedef __attribute__((ext_vector_type(4))) float f32x4;   // MFMA C/D frag

#define DEVINL static __device__ __forceinline__
#define MFMA __builtin_amdgcn_mfma_f32_16x16x32_bf16

DEVINL u16 f2bf(float f){ u32 x = __float_as_uint(f); return (u16)((x + 0x7fffu + ((x>>16)&1u)) >> 16); }
DEVINL float bf2f(u16 u){ return __uint_as_float(((u32)u) << 16); }
DEVINL u32 pack2(float a, float b){ return (u32)f2bf(a) | ((u32)f2bf(b) << 16); }
DEVINL float sigm(float x){ return 1.f/(1.f + __expf(-x)); }
DEVINL float tanhs(float x){ float xc = fminf(fmaxf(x,-15.f),15.f); float e = __expf(2.f*xc); return (e-1.f)/(e+1.f); }
DEVINL void g_store(u32* p, u32 v){ __hip_atomic_store(p, v, __ATOMIC_RELAXED, __HIP_MEMORY_SCOPE_AGENT); }
DEVINL u32  g_load(const u32* p){ return __hip_atomic_load(p, __ATOMIC_RELAXED, __HIP_MEMORY_SCOPE_AGENT); }

// ---------------- prep: pack weights to bf16 with row permutation j' = u*4+gate
// matrix order m: 0 eIH_l0, 1 eHH_l0, 2 eIH_l1, 3 eHH_l1, 4 dIH_l0, 5 dHH_l0, 6 dIH_l1, 7 dHH_l1
__global__ void pack_all(const float* __restrict__ eih, const float* __restrict__ ehh,
                         const float* __restrict__ dih, const float* __restrict__ dhh,
                         const float* __restrict__ ebi, const float* __restrict__ ebh,
                         const float* __restrict__ dbi, const float* __restrict__ dbh,
                         u16* __restrict__ wout, float* __restrict__ bout,
                         u32* __restrict__ flags){
  int blk = blockIdx.x, t = threadIdx.x;
  if (blk < 8192){
    int m = blk >> 10, j2 = blk & 1023;
    const float* base = (m < 4) ? ((m & 1) ? ehh : eih) : ((m & 1) ? dhh : dih);
    const float* S = base + (size_t)((m >> 1) & 1) * 262144;  // layer select
    int u = j2 >> 2, g = j2 & 3, j = g*256 + u;
    wout[(size_t)blk*256 + t] = f2bf(S[(size_t)j*256 + t]);
  } else if (blk < 8208){
    int idx = (blk - 8192)*256 + t;             // 0..4095 : [phase][layer][j']
    int phase = idx >> 11, l = (idx >> 10) & 1, j2 = idx & 1023;
    int u = j2 >> 2, g = j2 & 3, j = g*256 + u;
    const float* bi = phase ? dbi : ebi;
    const float* bh = phase ? dbh : ebh;
    bout[idx] = bi[l*1024 + j] + bh[l*1024 + j];
  } else {
    for (int i = t; i < 2048; i += 256) flags[i] = 0u;   // flag reset EVERY call
  }
}

struct SM {
  u16   A1[16][520];      // [x(t) 0..255 | h1(t-1) 256..511] bf16, pad 520 (2-way banks, free)
  u16   A2[16][520];      // [h1(t) 0..255 | h2(t-1) 256..511]
  float fcw[4][256];
  float fcb[4];
  int   tok[63][16];
};

__global__ void __launch_bounds__(512, 2)
lstm_main(const int* __restrict__ src, const float* __restrict__ enc_emb,
          const float* __restrict__ dec_emb, const u16* __restrict__ wpack,
          const float* __restrict__ bpack, const float* __restrict__ fcW,
          const float* __restrict__ fcb, float* __restrict__ out,
          u32* __restrict__ H1, u32* __restrict__ H2, u32* __restrict__ flags)
{
  __shared__ SM sm;
  const int tid  = threadIdx.x;
  const int wv   = tid >> 6;          // wave 0..7
  const int lane = tid & 63;
  const int agrp = lane >> 4;         // k-group / D row-block
  const int n    = lane & 15;         // batch row (MFMA N col)
  const int gid  = blockIdx.x & 31;   // batch group
  const int w    = blockIdx.x >> 5;   // column-slice id 0..7 (same XCD within group)
  const int wgb0 = gid << 4;
  const int xr   = tid >> 5, xc = (tid & 31) << 3;      // x-gather: row, col8
  const int jrow = (w << 7) + (wv << 4) + n;            // permuted gate row j'
  const int uu   = (w << 5) + (wv << 2) + agrp;         // unit owned by lane
  const int pw   = (w << 4) + (wv << 1) + (agrp >> 1);  // u32 word in H slice

  // ---- prologue staging
  for (int i = tid; i < 1008; i += 512){
    int s = i >> 4, b = i & 15;
    int t = (s < 31) ? (31 - s) : (s - 31);   // enc reversed, then dec forward
    sm.tok[s][b] = src[t*512 + wgb0 + b];
  }
  for (int i = tid; i < 1024; i += 512) ((float*)sm.fcw)[i] = fcW[i];
  if (tid < 4) sm.fcb[tid] = fcb[tid];
  for (int i = tid; i < 2048; i += 512){              // h1(-1)=h2(-1)=0
    int r = i >> 7, cc = (i & 127) << 1;
    *(u32*)&sm.A1[r][256 + cc] = 0u;
    *(u32*)&sm.A2[r][256 + cc] = 0u;
  }
  __syncthreads();
  { // x(0)
    int tk = sm.tok[0][xr];
    const float* e = enc_emb + (size_t)tk*256 + xc;
    float4 v0 = *(const float4*)e, v1 = *(const float4*)(e + 4);
    u32* d = (u32*)&sm.A1[xr][xc];
    d[0]=pack2(v0.x,v0.y); d[1]=pack2(v0.z,v0.w); d[2]=pack2(v1.x,v1.y); d[3]=pack2(v1.z,v1.w);
  }

  // ---- weight-stationary register state: 128 VGPRs of W + 8 of bias
  bf16x8 W[2][16];           // [layer][kk]
  float4 br[2];
  float  c1 = 0.f, c2 = 0.f;

  auto LOADW = [&](int ph){
    const u16* base = wpack + (size_t)ph * 1048576;
    #pragma unroll
    for (int l = 0; l < 2; l++){
      #pragma unroll
      for (int kk = 0; kk < 16; kk++){
        const u16* mp = base + (size_t)((l << 1) + (kk >> 3))*262144
                      + (size_t)jrow*256 + ((kk & 7) << 5) + (agrp << 3);
        W[l][kk] = *(const bf16x8*)mp;
      }
      br[l] = *(const float4*)(bpack + (((ph << 1) + l) << 10) + (uu << 2));
    }
  };
  LOADW(0);
  __syncthreads();

  for (int t = 0; t < 63; ++t){
    if (t == 31) LOADW(1);                     // enc -> dec phase switch
    // prefetch x(t+1) into regs (hides under MFMA + LDS reads)
    float4 xv0, xv1; const bool hasx = (t + 1) < 63;
    if (hasx){
      int tk = sm.tok[t+1][xr];
      const float* e = ((t+1) < 31 ? enc_emb : dec_emb) + (size_t)tk*256 + xc;
      xv0 = *(const float4*)e; xv1 = *(const float4*)(e + 4);
    }
    // ---- layer 1: D = W1 * [x(t); h1(t-1)]
    f32x4 acc = {0.f,0.f,0.f,0.f};
    #pragma unroll
    for (int kk = 0; kk < 16; kk++){
      bf16x8 b = *(const bf16x8*)&sm.A1[n][(kk << 5) + (agrp << 3)];
      acc = MFMA(W[0][kk], b, acc, 0, 0, 0);
    }
    { // gate1: lane owns (unit uu, row n); publish h1(t) slice
      float I = sigm(acc[0] + br[0].x), F = sigm(acc[1] + br[0].y);
      float G = tanhs(acc[2] + br[0].z), O = sigm(acc[3] + br[0].w);
      float cn = F*c1 + I*G; c1 = cn;
      u16 hb = f2bf(O * tanhs(cn));
      u32 other = (u32)__shfl_xor((int)(u32)hb, 16);
      if ((agrp & 1) == 0){
        u32 hv = (u32)hb | (other << 16);
        g_store(H1 + ((size_t)(t & 1)*32 + gid)*2048 + n*128 + pw, hv);
      }
    }
    __syncthreads();                                           // A: h1 stores drained
    if (tid == 0) g_store(&flags[gid*16 + w], (u32)(t + 1));
    if (tid < 64){                                             // wave0: poll F1>=t+1, F2>=t
      u32 tgt = (lane < 8) ? (u32)(t + 1) : (u32)t;
      bool mine = lane < 16;
      for (;;){
        u32 v = mine ? g_load(&flags[gid*16 + lane]) : 0u;
        int ok = (!mine) || (v >= tgt);
        if (__all(ok)) break;
        __builtin_amdgcn_s_sleep(2);
      }
    }
    __syncthreads();                                           // B
    { // readback: h1(t) -> A2 lo + A1 hi; h2(t-1) -> A2 hi; x(t+1) -> A1 lo
      const u32* h1r = H1 + ((size_t)(t & 1)*32 + gid)*2048;
      for (int i = tid; i < 2048; i += 512){
        int r = i >> 7, p = i & 127;
        u32 v = g_load(h1r + i);
        *(u32*)&sm.A2[r][p << 1] = v;
        *(u32*)&sm.A1[r][256 + (p << 1)] = v;
      }
      if (t > 0){
        const u32* h2r = H2 + ((size_t)((t + 1) & 1)*32 + gid)*2048;
        for (int i = tid; i < 2048; i += 512){
          int r = i >> 7, p = i & 127;
          *(u32*)&sm.A2[r][256 + (p << 1)] = g_load(h2r + i);
        }
      }
      if (hasx){
        u32* d = (u32*)&sm.A1[xr][xc];
        d[0]=pack2(xv0.x,xv0.y); d[1]=pack2(xv0.z,xv0.w);
        d[2]=pack2(xv1.x,xv1.y); d[3]=pack2(xv1.z,xv1.w);
      }
    }
    __syncthreads();                                           // C
    // ---- fc + log_softmax for step t-1 (h2(t-1) now in A2 hi); 2 rows per WG
    if (t >= 32 && tid < 8){
      int b = (w << 1) + (tid >> 2), v = tid & 3;
      float s = sm.fcb[v];
      #pragma unroll
      for (int q = 0; q < 32; ++q){
        bf16x8 hv = *(const bf16x8*)&sm.A2[b][256 + (q << 3)];
        const float* wr = &sm.fcw[v][q << 3];
        s += bf2f((u16)hv[0])*wr[0] + bf2f((u16)hv[1])*wr[1]
           + bf2f((u16)hv[2])*wr[2] + bf2f((u16)hv[3])*wr[3]
           + bf2f((u16)hv[4])*wr[4] + bf2f((u16)hv[5])*wr[5]
           + bf2f((u16)hv[6])*wr[6] + bf2f((u16)hv[7])*wr[7];
      }
      float m = fmaxf(s, __shfl_xor(s, 1)); m = fmaxf(m, __shfl_xor(m, 2));
      float e = __expf(s - m);
      float es = e + __shfl_xor(e, 1); es += __shfl_xor(es, 2);
      out[((size_t)(t - 32)*512 + wgb0 + b)*4 + v] = s - m - __logf(es);
    }
    // ---- layer 2: D = W2 * [h1(t); h2(t-1)]
    f32x4 acc2 = {0.f,0.f,0.f,0.f};
    #pragma unroll
    for (int kk = 0; kk < 16; kk++){
      bf16x8 b = *(const bf16x8*)&sm.A2[n][(kk << 5) + (agrp << 3)];
      acc2 = MFMA(W[1][kk], b, acc2, 0, 0, 0);
    }
    { // gate2: publish h2(t) slice
      float I = sigm(acc2[0] + br[1].x), F = sigm(acc2[1] + br[1].y);
      float G = tanhs(acc2[2] + br[1].z), O = sigm(acc2[3] + br[1].w);
      float cn = F*c2 + I*G; c2 = cn;
      u16 hb = f2bf(O * tanhs(cn));
      u32 other = (u32)__shfl_xor((int)(u32)hb, 16);
      if ((agrp & 1) == 0){
        u32 hv = (u32)hb | (other << 16);
        g_store(H2 + ((size_t)(t & 1)*32 + gid)*2048 + n*128 + pw, hv);
      }
    }
    __syncthreads();                                           // D: h2 stores drained
    if (tid == 0) g_store(&flags[gid*16 + 8 + w], (u32)(t + 1));
  }

  // ---- tail: fc for t=62 (needs h2(62), parity 0)
  if (tid < 64){
    bool mine = (lane >= 8 && lane < 16);
    for (;;){
      u32 v = mine ? g_load(&flags[gid*16 + lane]) : 0u;
      int ok = (!mine) || (v >= 63u);
      if (__all(ok)) break;
      __builtin_amdgcn_s_sleep(2);
    }
  }
  __syncthreads();
  {
    const u32* h2r = H2 + (size_t)gid*2048;                    // parity 62&1 = 0
    for (int i = tid; i < 2048; i += 512){
      int r = i >> 7, p = i & 127;
      *(u32*)&sm.A2[r][256 + (p << 1)] = g_load(h2r + i);
    }
  }
  __syncthreads();
  if (tid < 8){
    int b = (w << 1) + (tid >> 2), v = tid & 3;
    float s = sm.fcb[v];
    #pragma unroll
    for (int q = 0; q < 32; ++q){
      bf16x8 hv = *(const bf16x8*)&sm.A2[b][256 + (q << 3)];
      const float* wr = &sm.fcw[v][q << 3];
      s += bf2f((u16)hv[0])*wr[0] + bf2f((u16)hv[1])*wr[1]
         + bf2f((u16)hv[2])*wr[2] + bf2f((u16)hv[3])*wr[3]
         + bf2f((u16)hv[4])*wr[4] + bf2f((u16)hv[5])*wr[5]
         + bf2f((u16)hv[6])*wr[6] + bf2f((u16)hv[7])*wr[7];
    }
    float m = fmaxf(s, __shfl_xor(s, 1)); m = fmaxf(m, __shfl_xor(m, 2));
    float e = __expf(s - m);
    float es = e + __shfl_xor(e, 1); es += __shfl_xor(es, 2);
    out[((size_t)31*512 + wgb0 + b)*4 + v] = s - m - __logf(es);
  }
}

extern "C" void kernel_launch(void* const* d_in, const int* in_sizes, int n_in,
                              void* d_out, int out_size, void* d_ws, size_t ws_size,
                              hipStream_t stream){
  const int*   src     = (const int*)  d_in[0];
  const float* enc_emb = (const float*)d_in[2];
  const float* enc_Wih = (const float*)d_in[3];
  const float* enc_Whh = (const float*)d_in[4];
  const float* enc_bih = (const float*)d_in[5];
  const float* enc_bhh = (const float*)d_in[6];
  const float* dec_emb = (const float*)d_in[7];
  const float* dec_Wih = (const float*)d_in[8];
  const float* dec_Whh = (const float*)d_in[9];
  const float* dec_bih = (const float*)d_in[10];
  const float* dec_bhh = (const float*)d_in[11];
  const float* fcW     = (const float*)d_in[12];
  const float* fcb     = (const float*)d_in[13];
  float* out = (float*)d_out;
  (void)in_sizes; (void)n_in; (void)out_size; (void)ws_size;

  // ws: wpack 4MB | bpack 16KB | H1 512KB (2-parity) | H2 512KB | flags 8KB  (~5.05MB)
  u16*   wpack = (u16*)d_ws;
  float* bpack = (float*)((char*)d_ws + 4194304);
  u32*   H1    = (u32*)((char*)d_ws + 4194304 + 16384);
  u32*   H2    = (u32*)((char*)d_ws + 4194304 + 16384 + 524288);
  u32*   flags = (u32*)((char*)d_ws + 4194304 + 16384 + 1048576);

  pack_all<<<8209, 256, 0, stream>>>(enc_Wih, enc_Whh, dec_Wih, dec_Whh,
                                     enc_bih, enc_bhh, dec_bih, dec_bhh,
                                     wpack, bpack, flags);
  lstm_main<<<256, 512, 0, stream>>>(src, enc_emb, dec_emb, wpack, bpack,
                                     fcW, fcb, out, H1, H2, flags);
}

// Round 4
// 489.482 us; speedup vs baseline: 7.8855x; 1.2404x over previous
//
// Round 4: one exchange per step. l1(t)+l2(t-1) batched (operands ready at step
// start), single flag+poll, readback both h1/h2 in one pass. 3 barriers/step.
// Per-layer LOADW between loop segments keeps W[2][16] (128 VGPR) resident.
#include <hip/hip_runtime.h>

typedef unsigned short u16;
typedef unsigned int   u32;
typedef __attribute__((ext_vector_type(8))) short bf16x8;  // 8 bf16 (4 VGPRs)
typedef __attribute__((ext_vector_type(4))) float f32x4;   // MFMA C/D frag

#define DEVINL static __device__ __forceinline__
#define MFMA __builtin_amdgcn_mfma_f32_16x16x32_bf16

DEVINL u16 f2bf(float f){ u32 x = __float_as_uint(f); return (u16)((x + 0x7fffu + ((x>>16)&1u)) >> 16); }
DEVINL float bf2f(u16 u){ return __uint_as_float(((u32)u) << 16); }
DEVINL u32 pack2(float a, float b){ return (u32)f2bf(a) | ((u32)f2bf(b) << 16); }
DEVINL float sigm(float x){ return 1.f/(1.f + __expf(-x)); }
DEVINL float tanhs(float x){ float xc = fminf(fmaxf(x,-15.f),15.f); float e = __expf(2.f*xc); return (e-1.f)/(e+1.f); }
DEVINL void g_store(u32* p, u32 v){ __hip_atomic_store(p, v, __ATOMIC_RELAXED, __HIP_MEMORY_SCOPE_AGENT); }
DEVINL u32  g_load(const u32* p){ return __hip_atomic_load(p, __ATOMIC_RELAXED, __HIP_MEMORY_SCOPE_AGENT); }

// ---------------- prep: pack weights to bf16 with row permutation j' = u*4+gate
// matrix order m: 0 eIH_l0, 1 eHH_l0, 2 eIH_l1, 3 eHH_l1, 4 dIH_l0, 5 dHH_l0, 6 dIH_l1, 7 dHH_l1
__global__ void pack_all(const float* __restrict__ eih, const float* __restrict__ ehh,
                         const float* __restrict__ dih, const float* __restrict__ dhh,
                         const float* __restrict__ ebi, const float* __restrict__ ebh,
                         const float* __restrict__ dbi, const float* __restrict__ dbh,
                         u16* __restrict__ wout, float* __restrict__ bout,
                         u32* __restrict__ flags){
  int blk = blockIdx.x, t = threadIdx.x;
  if (blk < 8192){
    int m = blk >> 10, j2 = blk & 1023;
    const float* base = (m < 4) ? ((m & 1) ? ehh : eih) : ((m & 1) ? dhh : dih);
    const float* S = base + (size_t)((m >> 1) & 1) * 262144;  // layer select
    int u = j2 >> 2, g = j2 & 3, j = g*256 + u;
    wout[(size_t)blk*256 + t] = f2bf(S[(size_t)j*256 + t]);
  } else if (blk < 8208){
    int idx = (blk - 8192)*256 + t;             // 0..4095 : [phase][layer][j']
    int phase = idx >> 11, l = (idx >> 10) & 1, j2 = idx & 1023;
    int u = j2 >> 2, g = j2 & 3, j = g*256 + u;
    const float* bi = phase ? dbi : ebi;
    const float* bh = phase ? dbh : ebh;
    bout[idx] = bi[l*1024 + j] + bh[l*1024 + j];
  } else {
    for (int i = t; i < 2048; i += 256) flags[i] = 0u;   // flag reset EVERY call
  }
}

struct SM {
  u16   A1[16][520];      // [x(t) 0..255 | h1(t-1) 256..511]
  u16   A2[16][520];      // [h1(t-1) 0..255 | h2(t-2) 256..511]
  float fcw[4][256];
  float fcb[4];
  int   tok[63][16];
};

__global__ void __launch_bounds__(512, 2)
lstm_main(const int* __restrict__ src, const float* __restrict__ enc_emb,
          const float* __restrict__ dec_emb, const u16* __restrict__ wpack,
          const float* __restrict__ bpack, const float* __restrict__ fcW,
          const float* __restrict__ fcb, float* __restrict__ out,
          u32* __restrict__ H1, u32* __restrict__ H2, u32* __restrict__ flags)
{
  __shared__ SM sm;
  const int tid  = threadIdx.x;
  const int wv   = tid >> 6;          // wave 0..7
  const int lane = tid & 63;
  const int agrp = lane >> 4;         // k-group
  const int n    = lane & 15;         // batch row
  const int gid  = blockIdx.x & 31;   // batch group (same XCD across slices)
  const int w    = blockIdx.x >> 5;   // column-slice 0..7
  const int wgb0 = gid << 4;
  const int xr   = tid >> 5, xc = (tid & 31) << 3;      // x-gather: row, col8
  const int jrow = (w << 7) + (wv << 4) + n;            // permuted gate row j'
  const int uu   = (w << 5) + (wv << 2) + agrp;         // unit owned by lane
  const int pw   = (w << 4) + (wv << 1) + (agrp >> 1);  // u32 word in H slice

  // ---- prologue staging
  for (int i = tid; i < 1008; i += 512){
    int s = i >> 4, b = i & 15;
    int t = (s < 31) ? (31 - s) : (s - 31);   // enc reversed, then dec forward
    sm.tok[s][b] = src[t*512 + wgb0 + b];
  }
  for (int i = tid; i < 1024; i += 512) ((float*)sm.fcw)[i] = fcW[i];
  if (tid < 4) sm.fcb[tid] = fcb[tid];
  for (int i = tid; i < 4096; i += 512){              // zero A1 hi + all A2
    int r = i >> 8, c2 = (i & 255) << 1;
    if (c2 < 256) *(u32*)&sm.A1[r][256 + (c2 & 254)] = 0u;
    *(u32*)&sm.A2[r][c2] = 0u;
  }
  __syncthreads();
  { // x(0)
    int tk = sm.tok[0][xr];
    const float* e = enc_emb + (size_t)tk*256 + xc;
    float4 v0 = *(const float4*)e, v1 = *(const float4*)(e + 4);
    u32* d = (u32*)&sm.A1[xr][xc];
    d[0]=pack2(v0.x,v0.y); d[1]=pack2(v0.z,v0.w); d[2]=pack2(v1.x,v1.y); d[3]=pack2(v1.z,v1.w);
  }

  // ---- weight-stationary registers: W[2][16] = 128 VGPR + 8 bias
  bf16x8 W[2][16];
  float4 br[2];
  float  c1 = 0.f, c2s = 0.f;

  auto LOADW_L = [&](int ph, int l){
    const u16* base = wpack + (size_t)ph * 1048576;
    #pragma unroll
    for (int kk = 0; kk < 16; kk++){
      const u16* mp = base + (size_t)((l << 1) + (kk >> 3))*262144
                    + (size_t)jrow*256 + ((kk & 7) << 5) + (agrp << 3);
      W[l][kk] = *(const bf16x8*)mp;
    }
    br[l] = *(const float4*)(bpack + (((ph << 1) + l) << 10) + (uu << 2));
  };
  LOADW_L(0, 0); LOADW_L(0, 1);
  __syncthreads();

  auto step = [&](int t){
    const bool hasx = (t + 1) < 63;
    float4 xv0, xv1;
    if (hasx){                                   // issue x(t+1) loads early
      int tk = sm.tok[t+1][xr];
      const float* e = ((t+1) < 31 ? enc_emb : dec_emb) + (size_t)tk*256 + xc;
      xv0 = *(const float4*)e; xv1 = *(const float4*)(e + 4);
    }
    // ---- phase0: l1(t) over A1=[x(t)|h1(t-1)], l2(t-1) over A2=[h1(t-1)|h2(t-2)]
    f32x4 a1 = {0.f,0.f,0.f,0.f}, a2 = {0.f,0.f,0.f,0.f};
    #pragma unroll
    for (int kk = 0; kk < 16; kk++){
      bf16x8 b1 = *(const bf16x8*)&sm.A1[n][(kk << 5) + (agrp << 3)];
      bf16x8 b2 = *(const bf16x8*)&sm.A2[n][(kk << 5) + (agrp << 3)];
      a1 = MFMA(W[0][kk], b1, a1, 0, 0, 0);
      a2 = MFMA(W[1][kk], b2, a2, 0, 0, 0);
    }
    { // gate1 -> publish h1(t)
      float I = sigm(a1[0] + br[0].x), F = sigm(a1[1] + br[0].y);
      float G = tanhs(a1[2] + br[0].z), O = sigm(a1[3] + br[0].w);
      float cn = F*c1 + I*G; c1 = cn;
      u16 hb = f2bf(O * tanhs(cn));
      u32 other = (u32)__shfl_xor((int)(u32)hb, 16);
      if ((agrp & 1) == 0)
        g_store(H1 + ((size_t)(t & 1)*32 + gid)*2048 + n*128 + pw, (u32)hb | (other << 16));
    }
    if (t > 0){ // gate2 -> publish h2(t-1)
      float I = sigm(a2[0] + br[1].x), F = sigm(a2[1] + br[1].y);
      float G = tanhs(a2[2] + br[1].z), O = sigm(a2[3] + br[1].w);
      float cn = F*c2s + I*G; c2s = cn;
      u16 hb = f2bf(O * tanhs(cn));
      u32 other = (u32)__shfl_xor((int)(u32)hb, 16);
      if ((agrp & 1) == 0)
        g_store(H2 + ((size_t)((t-1) & 1)*32 + gid)*2048 + n*128 + pw, (u32)hb | (other << 16));
    }
    __syncthreads();                                           // SA: publishes drained
    if (tid == 0) g_store(&flags[gid*8 + w], (u32)(t + 1));
    if (hasx){                                                 // shadow: x(t+1) -> A1 lo
      u32* d = (u32*)&sm.A1[xr][xc];
      d[0]=pack2(xv0.x,xv0.y); d[1]=pack2(xv0.z,xv0.w);
      d[2]=pack2(xv1.x,xv1.y); d[3]=pack2(xv1.z,xv1.w);
    }
    if (tid < 64){                                             // wave0: poll all 8 flags
      const u32 tgt = (u32)(t + 1);
      const bool mine = lane < 8;
      for (;;){
        u32 v = mine ? g_load(&flags[gid*8 + lane]) : tgt;
        if (__all(v >= tgt)) break;
        __builtin_amdgcn_s_sleep(1);
      }
    }
    __syncthreads();                                           // SC
    { // readback: h1(t)->A1hi+A2lo; h2(t-1)->A2hi
      const u32* h1r = H1 + ((size_t)(t & 1)*32 + gid)*2048;
      const u32* h2r = H2 + ((size_t)((t-1) & 1)*32 + gid)*2048;
      const int q = tid << 2, r = q >> 7, p = q & 127;
      u32 v0 = g_load(h1r+q), v1 = g_load(h1r+q+1), v2 = g_load(h1r+q+2), v3 = g_load(h1r+q+3);
      u32 w0=0, w1=0, w2=0, w3=0;
      if (t > 0){ w0 = g_load(h2r+q); w1 = g_load(h2r+q+1); w2 = g_load(h2r+q+2); w3 = g_load(h2r+q+3); }
      u32* dA2lo = (u32*)&sm.A2[r][p << 1];
      u32* dA1hi = (u32*)&sm.A1[r][256 + (p << 1)];
      dA2lo[0]=v0; dA2lo[1]=v1; dA2lo[2]=v2; dA2lo[3]=v3;
      dA1hi[0]=v0; dA1hi[1]=v1; dA1hi[2]=v2; dA1hi[3]=v3;
      if (t > 0){
        u32* dA2hi = (u32*)&sm.A2[r][256 + (p << 1)];
        dA2hi[0]=w0; dA2hi[1]=w1; dA2hi[2]=w2; dA2hi[3]=w3;
      }
    }
    __syncthreads();                                           // SD
    if (t >= 32 && tid < 8){                                   // fc(t-1) -> out row t-32
      int b = (w << 1) + (tid >> 2), v = tid & 3;
      float s = sm.fcb[v];
      #pragma unroll
      for (int q8 = 0; q8 < 32; ++q8){
        bf16x8 hv = *(const bf16x8*)&sm.A2[b][256 + (q8 << 3)];
        const float* wr = &sm.fcw[v][q8 << 3];
        s += bf2f((u16)hv[0])*wr[0] + bf2f((u16)hv[1])*wr[1]
           + bf2f((u16)hv[2])*wr[2] + bf2f((u16)hv[3])*wr[3]
           + bf2f((u16)hv[4])*wr[4] + bf2f((u16)hv[5])*wr[5]
           + bf2f((u16)hv[6])*wr[6] + bf2f((u16)hv[7])*wr[7];
      }
      float m = fmaxf(s, __shfl_xor(s, 1)); m = fmaxf(m, __shfl_xor(m, 2));
      float e = __expf(s - m);
      float es = e + __shfl_xor(e, 1); es += __shfl_xor(es, 2);
      out[((size_t)(t - 32)*512 + wgb0 + b)*4 + v] = s - m - __logf(es);
    }
  };

  for (int t = 0; t <= 30; ++t) step(t);
  LOADW_L(1, 0);            // dec W1 (l1(31) is first decoder step; l2(30) still enc)
  step(31);
  LOADW_L(1, 1);            // dec W2 (first used by l2(31) at step 32)
  for (int t = 32; t <= 62; ++t) step(t);

  // ---- tail: l2(62) + fc(62)
  {
    f32x4 a2 = {0.f,0.f,0.f,0.f};
    #pragma unroll
    for (int kk = 0; kk < 16; kk++){
      bf16x8 b2 = *(const bf16x8*)&sm.A2[n][(kk << 5) + (agrp << 3)];
      a2 = MFMA(W[1][kk], b2, a2, 0, 0, 0);
    }
    float I = sigm(a2[0] + br[1].x), F = sigm(a2[1] + br[1].y);
    float G = tanhs(a2[2] + br[1].z), O = sigm(a2[3] + br[1].w);
    float cn = F*c2s + I*G;
    u16 hb = f2bf(O * tanhs(cn));
    u32 other = (u32)__shfl_xor((int)(u32)hb, 16);
    if ((agrp & 1) == 0)
      g_store(H2 + (size_t)gid*2048 + n*128 + pw, (u32)hb | (other << 16));  // parity 62&1=0
  }
  __syncthreads();
  if (tid == 0) g_store(&flags[gid*8 + w], 64u);
  if (tid < 64){
    const bool mine = lane < 8;
    for (;;){
      u32 v = mine ? g_load(&flags[gid*8 + lane]) : 64u;
      if (__all(v >= 64u)) break;
      __builtin_amdgcn_s_sleep(1);
    }
  }
  __syncthreads();
  {
    const u32* h2r = H2 + (size_t)gid*2048;
    const int q = tid << 2, r = q >> 7, p = q & 127;
    u32 w0 = g_load(h2r+q), w1 = g_load(h2r+q+1), w2 = g_load(h2r+q+2), w3 = g_load(h2r+q+3);
    u32* dA2hi = (u32*)&sm.A2[r][256 + (p << 1)];
    dA2hi[0]=w0; dA2hi[1]=w1; dA2hi[2]=w2; dA2hi[3]=w3;
  }
  __syncthreads();
  if (tid < 8){
    int b = (w << 1) + (tid >> 2), v = tid & 3;
    float s = sm.fcb[v];
    #pragma unroll
    for (int q8 = 0; q8 < 32; ++q8){
      bf16x8 hv = *(const bf16x8*)&sm.A2[b][256 + (q8 << 3)];
      const float* wr = &sm.fcw[v][q8 << 3];
      s += bf2f((u16)hv[0])*wr[0] + bf2f((u16)hv[1])*wr[1]
         + bf2f((u16)hv[2])*wr[2] + bf2f((u16)hv[3])*wr[3]
         + bf2f((u16)hv[4])*wr[4] + bf2f((u16)hv[5])*wr[5]
         + bf2f((u16)hv[6])*wr[6] + bf2f((u16)hv[7])*wr[7];
    }
    float m = fmaxf(s, __shfl_xor(s, 1)); m = fmaxf(m, __shfl_xor(m, 2));
    float e = __expf(s - m);
    float es = e + __shfl_xor(e, 1); es += __shfl_xor(es, 2);
    out[((size_t)31*512 + wgb0 + b)*4 + v] = s - m - __logf(es);
  }
}

extern "C" void kernel_launch(void* const* d_in, const int* in_sizes, int n_in,
                              void* d_out, int out_size, void* d_ws, size_t ws_size,
                              hipStream_t stream){
  const int*   src     = (const int*)  d_in[0];
  const float* enc_emb = (const float*)d_in[2];
  const float* enc_Wih = (const float*)d_in[3];
  const float* enc_Whh = (const float*)d_in[4];
  const float* enc_bih = (const float*)d_in[5];
  const float* enc_bhh = (const float*)d_in[6];
  const float* dec_emb = (const float*)d_in[7];
  const float* dec_Wih = (const float*)d_in[8];
  const float* dec_Whh = (const float*)d_in[9];
  const float* dec_bih = (const float*)d_in[10];
  const float* dec_bhh = (const float*)d_in[11];
  const float* fcW     = (const float*)d_in[12];
  const float* fcb     = (const float*)d_in[13];
  float* out = (float*)d_out;
  (void)in_sizes; (void)n_in; (void)out_size; (void)ws_size;

  // ws: wpack 4MB | bpack 16KB | H1 512KB (2-parity) | H2 512KB | flags 8KB
  u16*   wpack = (u16*)d_ws;
  float* bpack = (float*)((char*)d_ws + 4194304);
  u32*   H1    = (u32*)((char*)d_ws + 4194304 + 16384);
  u32*   H2    = (u32*)((char*)d_ws + 4194304 + 16384 + 524288);
  u32*   flags = (u32*)((char*)d_ws + 4194304 + 16384 + 1048576);

  pack_all<<<8209, 256, 0, stream>>>(enc_Wih, enc_Whh, dec_Wih, dec_Whh,
                                     enc_bih, enc_bhh, dec_bih, dec_bhh,
                                     wpack, bpack, flags);
  lstm_main<<<256, 512, 0, stream>>>(src, enc_emb, dec_emb, wpack, bpack,
                                     fcW, fcb, out, H1, H2, flags);
}